// Round 11
// baseline (211.145 us; speedup 1.0000x reference)
//
#include <hip/hip_runtime.h>
#include <hip/hip_bf16.h>
#include <math.h>

typedef _Float16 f16;
typedef _Float16 f16x8 __attribute__((ext_vector_type(8)));
typedef _Float16 f16x4 __attribute__((ext_vector_type(4)));
typedef float f32x4 __attribute__((ext_vector_type(4)));

#define MFMA(a, b, c) __builtin_amdgcn_mfma_f32_16x16x32_f16((a), (b), (c), 0, 0, 0)

constexpr int Dd = 64;
constexpr int Hh = 128;
constexpr int Nn = 4096;
constexpr int NT = 32;  // fb tile
constexpr float SLP = 0.2f;
constexpr float INV2K = 1.0f / 2048.0f;

// Per-d f16 layout in d_ws (element offsets), chunked layout:
//   [0,16384)     W1: c0 = rows 0..63 (hi 4096 swzK64 | lo 4096), c1 = rows 64..127
//   [16384,49152) W2: c0..c3, chunk c = rows 32c..32c+31 (hi 4096 swz | lo 4096)
//   [49152,81920) W3: c0..c3 same
constexpr int PD = 81920;
constexpr size_t W1L_OFF = (size_t)Dd * PD * 2;  // bytes; then w1last f32[64][128]
constexpr size_t WS_NEEDED = W1L_OFF + (size_t)Dd * Hh * 4;

__device__ __forceinline__ int swz(int r, int c) {
  return (r << 7) + ((((c >> 3) ^ (r & 15)) << 3) | (c & 7));
}
__device__ __forceinline__ int swzK64(int r, int c) {
  return (r << 6) + (((((c >> 3) ^ r) & 7) << 3) | (c & 7));
}
__device__ __forceinline__ int swzF(int n, int h) {
  return (n << 7) + ((((h >> 2) ^ n) & 31) << 2) + (h & 3);
}

struct HL { f16 h, l; };
__device__ __forceinline__ HL split(float v) {
  HL r;
  r.h = (f16)v;
  r.l = (f16)((v - (float)r.h) * 2048.0f);
  return r;
}

// Async contiguous global->LDS, 512 threads: nbytes multiple of 8192
__device__ __forceinline__ void cp_lds_async512(const void* g, void* l, int nbytes, int tid) {
  const int lane = tid & 63, wv = tid >> 6;
  for (int base = wv * 1024; base < nbytes; base += 8192) {
    __builtin_amdgcn_global_load_lds(
        (const __attribute__((address_space(1))) void*)((const char*)g + base + lane * 16),
        (__attribute__((address_space(3))) void*)((char*)l + base), 16, 0, 0);
  }
}

// ---------------- preprocess: chunked W2/W3 layout (32-row chunks) -----------
__global__ __launch_bounds__(256)
void prep_kernel(const float* __restrict__ W1, const float* __restrict__ W2,
                 const float* __restrict__ W3, f16* __restrict__ wsf,
                 float* __restrict__ w1lg, float* __restrict__ out_log) {
  const int gid = blockIdx.x * 256 + threadIdx.x;  // [0, 655360)
  if (gid < Dd * Hh) w1lg[gid] = W1[(gid >> 7) * 8320 + (gid & 127) * 65 + 64];
  if (gid < Nn) out_log[gid] = 0.f;

  const int d = gid / 10240;
  const int r = gid - d * 10240;
  f16* outd = wsf + (size_t)d * PD;
  float vv[8];
  f16* dst;
  int plane;
  if (r < 2048) {
    // W1: two 64-row chunks, swzK64
    int rem = r & 1023;
    int hf = r >> 10;
    plane = rem >> 9;
    int j = rem & 511;
    int row = j >> 3, sc = j & 7;
    int h = hf * 64 + row;
    int k0 = (sc ^ (row & 7)) << 3;
    const float* src = W1 + d * 8320 + h * 65 + k0;
#pragma unroll
    for (int e = 0; e < 8; e++) vv[e] = src[e];
    dst = outd + r * 8;
  } else {
    // W2/W3: 4 chunks of 32 rows each; chunk = hi 4096 (swz) | lo 4096
    int r2 = r - 2048;            // [0, 8192)
    int wmat = r2 >> 12;          // 0=W2, 1=W3
    int rr4 = r2 & 4095;
    int chunk = rr4 >> 10;        // 0..3
    int rr = rr4 & 1023;          // within 8192-elem chunk (1024 x 8)
    plane = rr >> 9;
    int j = rr & 511;
    int row = j >> 4, sc = j & 15;  // row 0..31
    int k0 = (sc ^ (row & 15)) << 3;
    const float* srcb = (wmat == 0 ? W2 : W3) + d * 16384;
    const float* src = srcb + (chunk * 32 + row) * 128 + k0;
    float4 v0 = *(const float4*)src, v1 = *(const float4*)(src + 4);
    vv[0] = v0.x; vv[1] = v0.y; vv[2] = v0.z; vv[3] = v0.w;
    vv[4] = v1.x; vv[5] = v1.y; vv[6] = v1.z; vv[7] = v1.w;
    dst = outd + 16384 + wmat * 32768 + chunk * 8192 + rr * 8;
  }
  if (plane) {
#pragma unroll
    for (int e = 0; e < 8; e++) {
      f16 hi = (f16)vv[e];
      vv[e] = (vv[e] - (float)hi) * 2048.0f;
    }
  }
  f16x8 o;
#pragma unroll
  for (int e = 0; e < 8; e++) o[e] = (f16)vv[e];
  *(f16x8*)dst = o;
}

// One 32-row weight chunk x full K=128 of MFMAs (hi plane at 0, lo at +4096).
__device__ __forceinline__ void mid_chunk(const f16* ws,
                                          const f16x8* axh, const f16x8* axl,
                                          const f16x8* ayh, const f16x8* ayl,
                                          int hrc, int quad,
                                          f32x4& aP, f32x4& aS, f32x4& dP, f32x4& dS) {
#pragma unroll
  for (int kc = 0; kc < 4; kc++) {
    int ko = kc * 32 + quad * 8;
    f16x8 wh = *(const f16x8*)&ws[swz(hrc, ko)];
    f16x8 wl = *(const f16x8*)&ws[4096 + swz(hrc, ko)];
    aP = MFMA(wh, axh[kc], aP);
    aS = MFMA(wl, axh[kc], aS);
    aS = MFMA(wh, axl[kc], aS);
    dP = MFMA(wh, ayh[kc], dP);
    dS = MFMA(wl, ayh[kc], dS);
    dS = MFMA(wh, ayl[kc], dS);
  }
}

// R21 = v5 (verified 154.3us) + L1 PHASE UNIFICATION: at entry DH/DL planes
// are empty (acts appear only at the L1 epilogue), so stage BOTH W1 chunks up
// front (c0->Ws, c1->DL plane), run both L1 MFMA half-phases back-to-back,
// and defer the (numerically identical) epilogue until after. Deletes 2 of
// L1's 5 barriers + the mid-L1 stage/drain pair; doubles the L1 MFMA burst.
// +16 VGPR (l1P/l1S -> [2][2]), ~80 total, no spill risk. Downstream (L2,
// fused L3/L4) byte-identical to v5.
__global__ __launch_bounds__(512, 4)
void np_prior_v6(const float* __restrict__ x, const f16* __restrict__ wsw,
                 const float* __restrict__ w1lg,
                 const float* __restrict__ b1, const float* __restrict__ b2,
                 const float* __restrict__ b3, const float* __restrict__ W4,
                 const float* __restrict__ b4,
                 float* __restrict__ out_res, float* __restrict__ out_log) {
  extern __shared__ char dsm[];        // 81920 B
  f16* AH = (f16*)dsm;                 // [0,16K): 64x128 f16 swz
  f16* AL = AH + 8192;                 // [16K,32K)
  f16* DH = AL + 8192;                 // [32K,48K)
  f16* DL = DH + 8192;                 // [48K,64K)
  f16* Ws = (f16*)(dsm + 65536);       // [64K,80K): 8192-f16 weight chunk

  const int tid = threadIdx.x, d = blockIdx.y, n0 = blockIdx.x * 64;
  const int lane = tid & 63, wv = tid >> 6, l15 = lane & 15, quad = lane >> 4;
  const int nt = wv & 3, wq = wv >> 2;  // 4 n-groups x 2 h-groups
  const int ra = nt * 16 + l15;         // 0..63
  const int hrc = wq * 16 + l15;        // 0..31 (row within 32-row chunk)

  const f16* wd = wsw + (size_t)d * PD;
  const float* w1l = w1lg + d * Hh;
  const float* b1d = b1 + d * Hh;
  const f32x4 zero = {0.f, 0.f, 0.f, 0.f};

  // Stage ALL of W1 (c0 -> Ws, c1 -> empty DL plane) + x
  cp_lds_async512(wd, Ws, 16384, tid);
  cp_lds_async512(wd + 8192, DL, 16384, tid);
  {
    int n = tid >> 3, k8 = (tid & 7) << 3;
    int ng = n0 + n, bb = ng >> 8, tt = ng & 255;
    const float* xs = &x[(bb * 257 + tt) * 64 + k8];
    float4 v0 = *(const float4*)xs, v1 = *(const float4*)(xs + 4);
    float va[8] = {v0.x, v0.y, v0.z, v0.w, v1.x, v1.y, v1.z, v1.w};
    f16x8 vh, vl;
#pragma unroll
    for (int e = 0; e < 8; e++) {
      HL s = split(va[e]);
      vh[e] = s.h; vl[e] = s.l;
    }
    int o = swz(n, k8);
    *(f16x8*)&AH[o] = vh;
    *(f16x8*)&AL[o] = vl;
  }
  float xtv;
  {
    int ng = n0 + ra, bb = ng >> 8, tt = ng & 255;
    xtv = x[(bb * 257 + tt + 1) * 64 + d];
  }
  __syncthreads();  // S1: all of W1 + x staged

  // ---- Layer 1 (K=64): both 64-row chunks, MFMAs back-to-back
  f16x8 l1xh[2], l1xl[2];
#pragma unroll
  for (int kc = 0; kc < 2; kc++) {
    int ko = kc * 32 + quad * 8;
    l1xh[kc] = *(const f16x8*)&AH[swz(ra, ko)];
    l1xl[kc] = *(const f16x8*)&AL[swz(ra, ko)];
  }
  f32x4 l1P[2][2], l1S[2][2];
#pragma unroll
  for (int cf = 0; cf < 2; cf++) {
    const f16* wb = (cf == 0) ? Ws : DL;
#pragma unroll
    for (int hf2 = 0; hf2 < 2; hf2++) {
      int hr64 = hf2 * 32 + hrc;
      l1P[cf][hf2] = zero; l1S[cf][hf2] = zero;
#pragma unroll
      for (int kc = 0; kc < 2; kc++) {
        int ko = kc * 32 + quad * 8;
        f16x8 wh = *(const f16x8*)&wb[swzK64(hr64, ko)];
        f16x8 wl = *(const f16x8*)&wb[4096 + swzK64(hr64, ko)];
        l1P[cf][hf2] = MFMA(wh, l1xh[kc], l1P[cf][hf2]);
        l1S[cf][hf2] = MFMA(wl, l1xh[kc], l1S[cf][hf2]);
        l1S[cf][hf2] = MFMA(wh, l1xl[kc], l1S[cf][hf2]);
      }
    }
  }
  __syncthreads();                              // A: W1 consumed; Ws+DL dead
  cp_lds_async512(wd + 16384, Ws, 16384, tid);  // W2c0 under epilogue

  // ---- L1 epilogue (deferred, numerically identical)
#pragma unroll
  for (int cf = 0; cf < 2; cf++) {
#pragma unroll
    for (int hf2 = 0; hf2 < 2; hf2++) {
      int hb = cf * 64 + hf2 * 32 + wq * 16 + quad * 4;
      float4 wv4 = *(const float4*)&w1l[hb];
      float4 bv4 = *(const float4*)&b1d[hb];
      f16x4 ah, al, dh, dl;
#pragma unroll
      for (int j = 0; j < 4; j++) {
        float w1j = (&wv4.x)[j];
        float p = l1P[cf][hf2][j] + l1S[cf][hf2][j] * INV2K + xtv * w1j + (&bv4.x)[j];
        float s = p > 0.f ? 1.f : SLP;
        HL av = split(p * s), dv = split(s * w1j);
        ah[j] = av.h; al[j] = av.l; dh[j] = dv.h; dl[j] = dv.l;
      }
      int o = swz(ra, hb);
      *(f16x4*)&AH[o] = ah; *(f16x4*)&AL[o] = al;
      *(f16x4*)&DH[o] = dh; *(f16x4*)&DL[o] = dl;
    }
  }
  __syncthreads();  // B: acts visible; W2c0 drained
  // here: acts(L1) ready, Ws = W2c0

  // ---- Layer 2: hoist acts once, then 4 weight chunks through the slot
  {
    f16x8 axh[4], axl[4], ayh[4], ayl[4];
#pragma unroll
    for (int kc = 0; kc < 4; kc++) {
      int ko = kc * 32 + quad * 8;
      axh[kc] = *(const f16x8*)&AH[swz(ra, ko)];
      axl[kc] = *(const f16x8*)&AL[swz(ra, ko)];
      ayh[kc] = *(const f16x8*)&DH[swz(ra, ko)];
      ayl[kc] = *(const f16x8*)&DL[swz(ra, ko)];
    }
    __syncthreads();  // hoists done, act LDS dead
    const float* b2d = b2 + d * Hh;
#pragma unroll 1
    for (int c = 0; c < 4; c++) {
      if (c > 0) {
        __syncthreads();
        cp_lds_async512(wd + 16384 + c * 8192, Ws, 16384, tid);
        __syncthreads();
      }
      f32x4 aP = zero, aS = zero, dP = zero, dS = zero;
      mid_chunk(Ws, axh, axl, ayh, ayl, hrc, quad, aP, aS, dP, dS);
      {
        int hb = c * 32 + wq * 16 + quad * 4;
        float4 bv4 = *(const float4*)&b2d[hb];
        f16x4 ah, al, dh, dl;
#pragma unroll
        for (int j = 0; j < 4; j++) {
          float p = aP[j] + aS[j] * INV2K + (&bv4.x)[j];
          float s = p > 0.f ? 1.f : SLP;
          float dd = s * (dP[j] + dS[j] * INV2K);
          HL av = split(p * s), dv = split(dd);
          ah[j] = av.h; al[j] = av.l; dh[j] = dv.h; dl[j] = dv.l;
        }
        int o = swz(ra, hb);
        *(f16x4*)&AH[o] = ah; *(f16x4*)&AL[o] = al;
        *(f16x4*)&DH[o] = dh; *(f16x4*)&DL[o] = dl;
      }
    }
  }
  __syncthreads();                                // L2 done; slot dead
  cp_lds_async512(wd + 49152, Ws, 16384, tid);    // W3c0 (under L3 hoist)

  // ---- Layer 3 fused with L4: dot against w4 in-register per chunk
  {
    f16x8 axh[4], axl[4], ayh[4], ayl[4];
#pragma unroll
    for (int kc = 0; kc < 4; kc++) {
      int ko = kc * 32 + quad * 8;
      axh[kc] = *(const f16x8*)&AH[swz(ra, ko)];
      axl[kc] = *(const f16x8*)&AL[swz(ra, ko)];
      ayh[kc] = *(const f16x8*)&DH[swz(ra, ko)];
      ayl[kc] = *(const f16x8*)&DL[swz(ra, ko)];
    }
    __syncthreads();  // W3c0 drained + hoists done; act planes dead
    const float* b3d = b3 + d * Hh;
    const float* w4d = W4 + d * Hh;
    float psr = 0.f, psd = 0.f;
#pragma unroll 1
    for (int c = 0; c < 4; c++) {
      if (c > 0) {
        __syncthreads();
        cp_lds_async512(wd + 49152 + c * 8192, Ws, 16384, tid);
        __syncthreads();
      }
      f32x4 aP = zero, aS = zero, dP = zero, dS = zero;
      mid_chunk(Ws, axh, axl, ayh, ayl, hrc, quad, aP, aS, dP, dS);
      {
        int hb = c * 32 + wq * 16 + quad * 4;
        float4 bv4 = *(const float4*)&b3d[hb];
        float4 wv4 = *(const float4*)&w4d[hb];
#pragma unroll
        for (int j = 0; j < 4; j++) {
          float p = aP[j] + aS[j] * INV2K + (&bv4.x)[j];
          float s = p > 0.f ? 1.f : SLP;
          psr += p * s * (&wv4.x)[j];
          psd += s * (dP[j] + dS[j] * INV2K) * (&wv4.x)[j];
        }
      }
    }
    // reduce across quads (butterfly over lane xor 16, 32)
    psr += __shfl_xor(psr, 16); psr += __shfl_xor(psr, 32);
    psd += __shfl_xor(psd, 16); psd += __shfl_xor(psd, 32);
    // cross-wq exchange via 512B buffer in the dead act region
    float* xch = (float*)dsm;  // [64][2] f32
    if (wq == 1 && quad == 0) {
      xch[ra * 2] = psr;
      xch[ra * 2 + 1] = psd;
    }
    __syncthreads();
    if (wq == 0 && quad == 0) {
      float sr = psr + xch[ra * 2];
      float sd = psd + xch[ra * 2 + 1];
      int ng = n0 + ra;
      out_res[ng * 64 + d] = sr + b4[d];
      atomicAdd(&out_log[ng], logf(fabsf(sd) + 1e-8f));
    }
  }
}

// ---------------- fallback (no-ws path, 256 threads, raw weights) -----------
__device__ __forceinline__ void stage_wf(f16* WH, f16* WL,
                                         const float* __restrict__ g, int tid) {
  for (int i = tid; i < 2048; i += 256) {
    int h = i >> 5, k4 = (i & 31) << 2;
    float4 v = ((const float4*)g)[i];
    HL a = split(v.x), b = split(v.y), c = split(v.z), e = split(v.w);
    int o = swz(h, k4);
    *(f16x4*)&WH[o] = f16x4{a.h, b.h, c.h, e.h};
    *(f16x4*)&WL[o] = f16x4{a.l, b.l, c.l, e.l};
  }
}

__device__ __forceinline__ void mid_mfma_half(
    const f16* AH, const f16* AL, const f16* DH, const f16* DL,
    const f16* WH, const f16* WL, int nt, int wq, int l15, int quad,
    f32x4* aP, f32x4* aS, f32x4* dP, f32x4* dS) {
#pragma unroll
  for (int kc = 0; kc < 4; kc++) {
    int ko = kc * 32 + quad * 8;
    int ra = nt * 16 + l15;
    f16x8 xh = *(const f16x8*)&AH[swz(ra, ko)];
    f16x8 xl = *(const f16x8*)&AL[swz(ra, ko)];
    f16x8 yh = *(const f16x8*)&DH[swz(ra, ko)];
    f16x8 yl = *(const f16x8*)&DL[swz(ra, ko)];
#pragma unroll
    for (int c2 = 0; c2 < 2; c2++) {
      int hr = (2 * wq + c2) * 16 + l15;
      f16x8 wh = *(const f16x8*)&WH[swz(hr, ko)];
      f16x8 wl = *(const f16x8*)&WL[swz(hr, ko)];
      aP[c2] = MFMA(wh, xh, aP[c2]);
      aS[c2] = MFMA(wl, xh, aS[c2]);
      aS[c2] = MFMA(wh, xl, aS[c2]);
      dP[c2] = MFMA(wh, yh, dP[c2]);
      dS[c2] = MFMA(wl, yh, dS[c2]);
      dS[c2] = MFMA(wh, yl, dS[c2]);
    }
  }
}

__global__ __launch_bounds__(256, 2)
void np_prior_fb(const float* __restrict__ x,
                 const float* __restrict__ W1, const float* __restrict__ b1,
                 const float* __restrict__ W2, const float* __restrict__ b2,
                 const float* __restrict__ W3, const float* __restrict__ b3,
                 const float* __restrict__ W4, const float* __restrict__ b4,
                 float* __restrict__ out_res, float* __restrict__ out_log) {
  __shared__ float4 smem[4096];
  f16* AH = (f16*)smem;
  f16* AL = AH + NT * 128;
  f16* DH = AL + NT * 128;
  f16* DL = DH + NT * 128;
  f16* WHp = (f16*)((char*)smem + 32768);
  f16* WLp = WHp + 64 * 128;
  float* A3F = (float*)smem;
  float* D3F = (float*)((char*)smem + 16384);

  const int tid = threadIdx.x, d = blockIdx.y, n0 = blockIdx.x * NT;
  const int lane = tid & 63, wv = tid >> 6, l15 = lane & 15, quad = lane >> 4;
  const int nt = wv & 1, wq = wv >> 1;

  const float* W1d = W1 + d * Hh * 65;
  const float* b1d = b1 + d * Hh;
  const f32x4 zero = {0.f, 0.f, 0.f, 0.f};

  for (int i = tid; i < NT * 16; i += 256) {
    int n = i >> 4, k4 = (i & 15) << 2;
    int ng = n0 + n, bb = ng >> 8, tt = ng & 255;
    float4 v = *(const float4*)&x[(bb * 257 + tt) * 64 + k4];
    HL a = split(v.x), b = split(v.y), c = split(v.z), e = split(v.w);
    int o = swz(n, k4);
    *(f16x4*)&AH[o] = f16x4{a.h, b.h, c.h, e.h};
    *(f16x4*)&AL[o] = f16x4{a.l, b.l, c.l, e.l};
  }
  float xtv;
  {
    int ng = n0 + nt * 16 + l15, bb = ng >> 8, tt = ng & 255;
    xtv = x[(bb * 257 + tt + 1) * 64 + d];
  }
  for (int i = tid; i < 64 * 64; i += 256) {
    int h = i >> 6, k = i & 63;
    HL s = split(W1d[h * 65 + k]);
    int o = swz(h, k);
    WHp[o] = s.h; WLp[o] = s.l;
  }
  __syncthreads();

  f32x4 l1P[2][2], l1S[2][2];
  for (int hf = 0; hf < 2; hf++) {
    if (hf == 1) {
      __syncthreads();
      for (int i = tid; i < 64 * 64; i += 256) {
        int h = i >> 6, k = i & 63;
        HL s = split(W1d[(64 + h) * 65 + k]);
        int o = swz(h, k);
        WHp[o] = s.h; WLp[o] = s.l;
      }
      __syncthreads();
    }
    l1P[hf][0] = zero; l1P[hf][1] = zero;
    l1S[hf][0] = zero; l1S[hf][1] = zero;
#pragma unroll
    for (int kc = 0; kc < 2; kc++) {
      int ko = kc * 32 + quad * 8;
      f16x8 xh = *(const f16x8*)&AH[swz(nt * 16 + l15, ko)];
      f16x8 xl = *(const f16x8*)&AL[swz(nt * 16 + l15, ko)];
#pragma unroll
      for (int c2 = 0; c2 < 2; c2++) {
        int hr = (2 * wq + c2) * 16 + l15;
        f16x8 wh = *(const f16x8*)&WHp[swz(hr, ko)];
        f16x8 wl = *(const f16x8*)&WLp[swz(hr, ko)];
        l1P[hf][c2] = MFMA(wh, xh, l1P[hf][c2]);
        l1S[hf][c2] = MFMA(wl, xh, l1S[hf][c2]);
        l1S[hf][c2] = MFMA(wh, xl, l1S[hf][c2]);
      }
    }
  }
  __syncthreads();

  {
    int n = nt * 16 + l15;
#pragma unroll
    for (int hf = 0; hf < 2; hf++)
#pragma unroll
      for (int c2 = 0; c2 < 2; c2++) {
        int hb = hf * 64 + (2 * wq + c2) * 16 + quad * 4;
        f16x4 ah, al, dh, dl;
#pragma unroll
        for (int j = 0; j < 4; j++) {
          int h = hb + j;
          float w1j = W1d[h * 65 + 64];
          float p = l1P[hf][c2][j] + l1S[hf][c2][j] * INV2K + xtv * w1j + b1d[h];
          float s = p > 0.f ? 1.f : SLP;
          HL av = split(p * s), dv = split(s * w1j);
          ah[j] = av.h; al[j] = av.l; dh[j] = dv.h; dl[j] = dv.l;
        }
        int o = swz(n, hb);
        *(f16x4*)&AH[o] = ah; *(f16x4*)&AL[o] = al;
        *(f16x4*)&DH[o] = dh; *(f16x4*)&DL[o] = dl;
      }
  }
  stage_wf(WHp, WLp, W2 + d * Hh * Hh, tid);
  __syncthreads();

  f32x4 aP[2][2], aS[2][2], dP[2][2], dS[2][2];
  for (int hf = 0; hf < 2; hf++) {
    if (hf == 1) {
      __syncthreads();
      stage_wf(WHp, WLp, W2 + d * Hh * Hh + 64 * 128, tid);
      __syncthreads();
    }
    aP[hf][0] = zero; aP[hf][1] = zero; aS[hf][0] = zero; aS[hf][1] = zero;
    dP[hf][0] = zero; dP[hf][1] = zero; dS[hf][0] = zero; dS[hf][1] = zero;
    mid_mfma_half(AH, AL, DH, DL, WHp, WLp, nt, wq, l15, quad,
                  aP[hf], aS[hf], dP[hf], dS[hf]);
  }
  __syncthreads();

  {
    const float* b2d = b2 + d * Hh;
    int n = nt * 16 + l15;
#pragma unroll
    for (int hf = 0; hf < 2; hf++)
#pragma unroll
      for (int c2 = 0; c2 < 2; c2++) {
        int hb = hf * 64 + (2 * wq + c2) * 16 + quad * 4;
        f16x4 ah, al, dh, dl;
#pragma unroll
        for (int j = 0; j < 4; j++) {
          int h = hb + j;
          float p = aP[hf][c2][j] + aS[hf][c2][j] * INV2K + b2d[h];
          float s = p > 0.f ? 1.f : SLP;
          float dd = s * (dP[hf][c2][j] + dS[hf][c2][j] * INV2K);
          HL av = split(p * s), dv = split(dd);
          ah[j] = av.h; al[j] = av.l; dh[j] = dv.h; dl[j] = dv.l;
        }
        int o = swz(n, hb);
        *(f16x4*)&AH[o] = ah; *(f16x4*)&AL[o] = al;
        *(f16x4*)&DH[o] = dh; *(f16x4*)&DL[o] = dl;
      }
  }
  stage_wf(WHp, WLp, W3 + d * Hh * Hh, tid);
  __syncthreads();

  for (int hf = 0; hf < 2; hf++) {
    if (hf == 1) {
      __syncthreads();
      stage_wf(WHp, WLp, W3 + d * Hh * Hh + 64 * 128, tid);
      __syncthreads();
    }
    aP[hf][0] = zero; aP[hf][1] = zero; aS[hf][0] = zero; aS[hf][1] = zero;
    dP[hf][0] = zero; dP[hf][1] = zero; dS[hf][0] = zero; dS[hf][1] = zero;
    mid_mfma_half(AH, AL, DH, DL, WHp, WLp, nt, wq, l15, quad,
                  aP[hf], aS[hf], dP[hf], dS[hf]);
  }
  __syncthreads();

  {
    const float* b3d = b3 + d * Hh;
    int n = nt * 16 + l15;
#pragma unroll
    for (int hf = 0; hf < 2; hf++)
#pragma unroll
      for (int c2 = 0; c2 < 2; c2++) {
        int hb = hf * 64 + (2 * wq + c2) * 16 + quad * 4;
        float4 pa, pd;
#pragma unroll
        for (int j = 0; j < 4; j++) {
          int h = hb + j;
          float p = aP[hf][c2][j] + aS[hf][c2][j] * INV2K + b3d[h];
          float s = p > 0.f ? 1.f : SLP;
          (&pa.x)[j] = p * s;
          (&pd.x)[j] = s * (dP[hf][c2][j] + dS[hf][c2][j] * INV2K);
        }
        *(float4*)&A3F[swzF(n, hb)] = pa;
        *(float4*)&D3F[swzF(n, hb)] = pd;
      }
  }
  __syncthreads();

  {
    int n = tid >> 3, oct = tid & 7;
    const float* w4d = W4 + d * Hh;
    float sr = 0.f, sd = 0.f;
#pragma unroll
    for (int i = 0; i < 4; i++) {
      int c = oct * 16 + i * 4;
      float4 va = *(const float4*)&A3F[swzF(n, c)];
      float4 vd = *(const float4*)&D3F[swzF(n, c)];
      float4 w = *(const float4*)&w4d[c];
      sr += va.x * w.x + va.y * w.y + va.z * w.z + va.w * w.w;
      sd += vd.x * w.x + vd.y * w.y + vd.z * w.z + vd.w * w.w;
    }
    sr += __shfl_xor(sr, 1); sr += __shfl_xor(sr, 2); sr += __shfl_xor(sr, 4);
    sd += __shfl_xor(sd, 1); sd += __shfl_xor(sd, 2); sd += __shfl_xor(sd, 4);
    if (oct == 0) {
      int ng = n0 + n;
      out_res[ng * 64 + d] = sr + b4[d];
      atomicAdd(&out_log[ng], logf(fabsf(sd) + 1e-8f));
    }
  }
}

extern "C" void kernel_launch(void* const* d_in, const int* in_sizes, int n_in,
                              void* d_out, int out_size, void* d_ws, size_t ws_size,
                              hipStream_t stream) {
  (void)in_sizes; (void)n_in; (void)out_size;
  const float* x  = (const float*)d_in[0];
  const float* W1 = (const float*)d_in[1];
  const float* b1 = (const float*)d_in[2];
  const float* W2 = (const float*)d_in[3];
  const float* b2 = (const float*)d_in[4];
  const float* W3 = (const float*)d_in[5];
  const float* b3 = (const float*)d_in[6];
  const float* W4 = (const float*)d_in[7];
  const float* b4 = (const float*)d_in[8];

  float* out_res = (float*)d_out;
  float* out_log = out_res + Nn * Dd;

  static int big_lds = -1;  // -1 unknown, 1 ok, 0 failed
  if (big_lds < 0) {
    big_lds = (hipFuncSetAttribute(
                   (const void*)np_prior_v6,
                   hipFuncAttributeMaxDynamicSharedMemorySize, 81920) ==
               hipSuccess)
                  ? 1
                  : 0;
  }

  if (ws_size >= WS_NEEDED && big_lds == 1) {
    f16* wsf = (f16*)d_ws;
    float* w1lg = (float*)((char*)d_ws + W1L_OFF);
    prep_kernel<<<2560, 256, 0, stream>>>(W1, W2, W3, wsf, w1lg, out_log);
    dim3 grid(Nn / 64, Dd);
    np_prior_v6<<<grid, 512, 81920, stream>>>(x, wsf, w1lg, b1, b2, b3, W4,
                                              b4, out_res, out_log);
  } else {
    hipMemsetAsync(out_log, 0, Nn * sizeof(float), stream);
    dim3 grid(Nn / NT, Dd);
    np_prior_fb<<<grid, 256, 0, stream>>>(x, W1, b1, W2, b2, W3, b3, W4, b4,
                                          out_res, out_log);
  }
}

// Round 13
// 209.676 us; speedup vs baseline: 1.0070x; 1.0070x over previous
//
#include <hip/hip_runtime.h>
#include <hip/hip_bf16.h>
#include <math.h>

typedef _Float16 f16;
typedef _Float16 f16x8 __attribute__((ext_vector_type(8)));
typedef _Float16 f16x4 __attribute__((ext_vector_type(4)));
typedef float f32x4 __attribute__((ext_vector_type(4)));

#define MFMA(a, b, c) __builtin_amdgcn_mfma_f32_16x16x32_f16((a), (b), (c), 0, 0, 0)

constexpr int Dd = 64;
constexpr int Hh = 128;
constexpr int Nn = 4096;
constexpr int NT = 32;  // fallback tile
constexpr float SLP = 0.2f;
constexpr float INV2K = 1.0f / 2048.0f;

// d_ws layout per latent d (f16 element offsets):
//   [0,16384)     W1 rows 0..63 then 64..127 (each: hi 4096 swzK64 | lo 4096)
//   [16384,49152) W2 chunks c0..c3 (32 rows each: hi 4096 swz | lo 4096)
//   [49152,81920) W3 chunks c0..c3 (same shape)
constexpr int PD = 81920;
constexpr size_t W1L_OFF = (size_t)Dd * PD * 2;  // bytes; then w1last f32[64][128]
constexpr size_t WS_NEEDED = W1L_OFF + (size_t)Dd * Hh * 4;

__device__ __forceinline__ int swz(int r, int c) {
  return (r << 7) + ((((c >> 3) ^ (r & 15)) << 3) | (c & 7));
}
__device__ __forceinline__ int swzK64(int r, int c) {
  return (r << 6) + (((((c >> 3) ^ r) & 7) << 3) | (c & 7));
}
__device__ __forceinline__ int swzF(int n, int h) {
  return (n << 7) + ((((h >> 2) ^ n) & 31) << 2) + (h & 3);
}

struct HL { f16 h, l; };
__device__ __forceinline__ HL split(float v) {
  HL r;
  r.h = (f16)v;
  r.l = (f16)((v - (float)r.h) * 2048.0f);
  return r;
}

// Contiguous async global->LDS for 512 threads; nbytes multiple of 8192.
__device__ __forceinline__ void cp_lds_async512(const void* g, void* l, int nbytes, int tid) {
  const int lane = tid & 63, wv = tid >> 6;
  for (int base = wv * 1024; base < nbytes; base += 8192) {
    __builtin_amdgcn_global_load_lds(
        (const __attribute__((address_space(1))) void*)((const char*)g + base + lane * 16),
        (__attribute__((address_space(3))) void*)((char*)l + base), 16, 0, 0);
  }
}

// ------------- preprocess (verified): build chunked f16 hi/lo planes --------
__global__ __launch_bounds__(256)
void prep_kernel(const float* __restrict__ W1, const float* __restrict__ W2,
                 const float* __restrict__ W3, f16* __restrict__ wsf,
                 float* __restrict__ w1lg, float* __restrict__ out_log) {
  const int gid = blockIdx.x * 256 + threadIdx.x;  // [0, 655360)
  if (gid < Dd * Hh) w1lg[gid] = W1[(gid >> 7) * 8320 + (gid & 127) * 65 + 64];
  if (gid < Nn) out_log[gid] = 0.f;

  const int d = gid / 10240;
  const int r = gid - d * 10240;
  f16* outd = wsf + (size_t)d * PD;
  float vv[8];
  f16* dst;
  int plane;
  if (r < 2048) {
    int rem = r & 1023;
    int hf = r >> 10;
    plane = rem >> 9;
    int j = rem & 511;
    int row = j >> 3, sc = j & 7;
    int h = hf * 64 + row;
    int k0 = (sc ^ (row & 7)) << 3;
    const float* src = W1 + d * 8320 + h * 65 + k0;
#pragma unroll
    for (int e = 0; e < 8; e++) vv[e] = src[e];
    dst = outd + r * 8;
  } else {
    int r2 = r - 2048;
    int wmat = r2 >> 12;
    int rr4 = r2 & 4095;
    int chunk = rr4 >> 10;
    int rr = rr4 & 1023;
    plane = rr >> 9;
    int j = rr & 511;
    int row = j >> 4, sc = j & 15;
    int k0 = (sc ^ (row & 15)) << 3;
    const float* srcb = (wmat == 0 ? W2 : W3) + d * 16384;
    const float* src = srcb + (chunk * 32 + row) * 128 + k0;
    float4 v0 = *(const float4*)src, v1 = *(const float4*)(src + 4);
    vv[0] = v0.x; vv[1] = v0.y; vv[2] = v0.z; vv[3] = v0.w;
    vv[4] = v1.x; vv[5] = v1.y; vv[6] = v1.z; vv[7] = v1.w;
    dst = outd + 16384 + wmat * 32768 + chunk * 8192 + rr * 8;
  }
  if (plane) {
#pragma unroll
    for (int e = 0; e < 8; e++) {
      f16 hi = (f16)vv[e];
      vv[e] = (vv[e] - (float)hi) * 2048.0f;
    }
  }
  f16x8 o;
#pragma unroll
  for (int e = 0; e < 8; e++) o[e] = (f16)vv[e];
  *(f16x8*)dst = o;
}

// Full-K MFMA sweep of one 32-row chunk (hi plane @0, lo plane @+4096).
__device__ __forceinline__ void mid_chunk(const f16* ws,
                                          const f16x8* axh, const f16x8* axl,
                                          const f16x8* ayh, const f16x8* ayl,
                                          int hrc, int quad,
                                          f32x4& aP, f32x4& aS, f32x4& dP, f32x4& dS) {
#pragma unroll
  for (int kc = 0; kc < 4; kc++) {
    int ko = kc * 32 + quad * 8;
    f16x8 wh = *(const f16x8*)&ws[swz(hrc, ko)];
    f16x8 wl = *(const f16x8*)&ws[4096 + swz(hrc, ko)];
    aP = MFMA(wh, axh[kc], aP);
    aS = MFMA(wl, axh[kc], aS);
    aS = MFMA(wh, axl[kc], aS);
    dP = MFMA(wh, ayh[kc], dP);
    dS = MFMA(wl, ayh[kc], dS);
    dS = MFMA(wh, ayl[kc], dS);
  }
}

// v7 (resubmitted with re-hashed source after an infra double-failure; kernel
// logic unchanged). Base = v6 @149.8us. Change vs v6: in each mid-layer chunk
// loop the iteration order becomes {MFMA; barrier; issue next stage; epilogue
// under the drain; barrier} instead of {epilogue; barrier; stage; barrier}.
// Barrier count identical, numerics bit-identical (epilogue writes act planes
// only; the stage writes Ws only); the six formerly-empty drain windows now
// contain the ~100-150-cycle epilogue VALU burst. Keeps v6's unified L1 and
// v5's fused L3/L4 tail.
__global__ __launch_bounds__(512, 4)
void np_prior_v7(const float* __restrict__ x, const f16* __restrict__ wsw,
                 const float* __restrict__ w1lg,
                 const float* __restrict__ b1, const float* __restrict__ b2,
                 const float* __restrict__ b3, const float* __restrict__ W4,
                 const float* __restrict__ b4,
                 float* __restrict__ out_res, float* __restrict__ out_log) {
  extern __shared__ char dsm[];        // 81920 B dynamic LDS
  f16* AH = (f16*)dsm;                 // act-hi  [0,16K)
  f16* AL = AH + 8192;                 // act-lo  [16K,32K)
  f16* DH = AL + 8192;                 // d-hi    [32K,48K)
  f16* DL = DH + 8192;                 // d-lo    [48K,64K)
  f16* Ws = (f16*)(dsm + 65536);       // weight slot [64K,80K)

  const int tid = threadIdx.x, d = blockIdx.y, n0 = blockIdx.x * 64;
  const int lane = tid & 63, wv = tid >> 6, l15 = lane & 15, quad = lane >> 4;
  const int nt = wv & 3, wq = wv >> 2;
  const int ra = nt * 16 + l15;
  const int hrc = wq * 16 + l15;

  const f16* wd = wsw + (size_t)d * PD;
  const float* w1l = w1lg + d * Hh;
  const float* b1d = b1 + d * Hh;
  const f32x4 zero = {0.f, 0.f, 0.f, 0.f};

  // Entry: W1 rows 0..63 -> Ws, rows 64..127 -> (empty) DL plane; x -> AH/AL.
  cp_lds_async512(wd, Ws, 16384, tid);
  cp_lds_async512(wd + 8192, DL, 16384, tid);
  {
    int n = tid >> 3, k8 = (tid & 7) << 3;
    int ng = n0 + n, bb = ng >> 8, tt = ng & 255;
    const float* xs = &x[(bb * 257 + tt) * 64 + k8];
    float4 v0 = *(const float4*)xs, v1 = *(const float4*)(xs + 4);
    float va[8] = {v0.x, v0.y, v0.z, v0.w, v1.x, v1.y, v1.z, v1.w};
    f16x8 vh, vl;
#pragma unroll
    for (int e = 0; e < 8; e++) {
      HL s = split(va[e]);
      vh[e] = s.h; vl[e] = s.l;
    }
    int o = swz(n, k8);
    *(f16x8*)&AH[o] = vh;
    *(f16x8*)&AL[o] = vl;
  }
  float xtv;
  {
    int ng = n0 + ra, bb = ng >> 8, tt = ng & 255;
    xtv = x[(bb * 257 + tt + 1) * 64 + d];
  }
  __syncthreads();  // W1 + x resident

  // Layer 1: both 64-row halves, MFMA bursts back-to-back.
  f16x8 l1xh[2], l1xl[2];
#pragma unroll
  for (int kc = 0; kc < 2; kc++) {
    int ko = kc * 32 + quad * 8;
    l1xh[kc] = *(const f16x8*)&AH[swz(ra, ko)];
    l1xl[kc] = *(const f16x8*)&AL[swz(ra, ko)];
  }
  f32x4 l1P[2][2], l1S[2][2];
#pragma unroll
  for (int cf = 0; cf < 2; cf++) {
    const f16* wb = (cf == 0) ? Ws : DL;
#pragma unroll
    for (int hf2 = 0; hf2 < 2; hf2++) {
      int hr64 = hf2 * 32 + hrc;
      l1P[cf][hf2] = zero; l1S[cf][hf2] = zero;
#pragma unroll
      for (int kc = 0; kc < 2; kc++) {
        int ko = kc * 32 + quad * 8;
        f16x8 wh = *(const f16x8*)&wb[swzK64(hr64, ko)];
        f16x8 wl = *(const f16x8*)&wb[4096 + swzK64(hr64, ko)];
        l1P[cf][hf2] = MFMA(wh, l1xh[kc], l1P[cf][hf2]);
        l1S[cf][hf2] = MFMA(wl, l1xh[kc], l1S[cf][hf2]);
        l1S[cf][hf2] = MFMA(wh, l1xl[kc], l1S[cf][hf2]);
      }
    }
  }
  __syncthreads();                              // W1 consumed; Ws and DL free
  cp_lds_async512(wd + 16384, Ws, 16384, tid);  // W2c0 issues under epilogue

  // Deferred L1 epilogue (numerically unchanged).
#pragma unroll
  for (int cf = 0; cf < 2; cf++) {
#pragma unroll
    for (int hf2 = 0; hf2 < 2; hf2++) {
      int hb = cf * 64 + hf2 * 32 + wq * 16 + quad * 4;
      float4 wv4 = *(const float4*)&w1l[hb];
      float4 bv4 = *(const float4*)&b1d[hb];
      f16x4 ah, al, dh, dl;
#pragma unroll
      for (int j = 0; j < 4; j++) {
        float w1j = (&wv4.x)[j];
        float p = l1P[cf][hf2][j] + l1S[cf][hf2][j] * INV2K + xtv * w1j + (&bv4.x)[j];
        float s = p > 0.f ? 1.f : SLP;
        HL av = split(p * s), dv = split(s * w1j);
        ah[j] = av.h; al[j] = av.l; dh[j] = dv.h; dl[j] = dv.l;
      }
      int o = swz(ra, hb);
      *(f16x4*)&AH[o] = ah; *(f16x4*)&AL[o] = al;
      *(f16x4*)&DH[o] = dh; *(f16x4*)&DL[o] = dl;
    }
  }
  __syncthreads();  // acts visible; W2c0 drained

  // Layer 2: hoist act fragments, then stream 4 chunks with covered drains.
  {
    f16x8 axh[4], axl[4], ayh[4], ayl[4];
#pragma unroll
    for (int kc = 0; kc < 4; kc++) {
      int ko = kc * 32 + quad * 8;
      axh[kc] = *(const f16x8*)&AH[swz(ra, ko)];
      axl[kc] = *(const f16x8*)&AL[swz(ra, ko)];
      ayh[kc] = *(const f16x8*)&DH[swz(ra, ko)];
      ayl[kc] = *(const f16x8*)&DL[swz(ra, ko)];
    }
    __syncthreads();  // fragments in registers; act LDS reusable
    const float* b2d = b2 + d * Hh;
#pragma unroll 1
    for (int c = 0; c < 4; c++) {
      f32x4 aP = zero, aS = zero, dP = zero, dS = zero;
      mid_chunk(Ws, axh, axl, ayh, ayl, hrc, quad, aP, aS, dP, dS);
      if (c < 3) {
        __syncthreads();  // every wave done reading Ws
        cp_lds_async512(wd + 16384 + (c + 1) * 8192, Ws, 16384, tid);
      }
      {
        int hb = c * 32 + wq * 16 + quad * 4;
        float4 bv4 = *(const float4*)&b2d[hb];
        f16x4 ah, al, dh, dl;
#pragma unroll
        for (int j = 0; j < 4; j++) {
          float p = aP[j] + aS[j] * INV2K + (&bv4.x)[j];
          float s = p > 0.f ? 1.f : SLP;
          float dd = s * (dP[j] + dS[j] * INV2K);
          HL av = split(p * s), dv = split(dd);
          ah[j] = av.h; al[j] = av.l; dh[j] = dv.h; dl[j] = dv.l;
        }
        int o = swz(ra, hb);
        *(f16x4*)&AH[o] = ah; *(f16x4*)&AL[o] = al;
        *(f16x4*)&DH[o] = dh; *(f16x4*)&DL[o] = dl;
      }
      if (c < 3) __syncthreads();  // stage fully drained
    }
  }
  __syncthreads();                                // L2 complete; Ws free
  cp_lds_async512(wd + 49152, Ws, 16384, tid);    // W3c0 under the L3 hoist

  // Layer 3 with fused L4 tail: per-chunk in-register dot against w4.
  {
    f16x8 axh[4], axl[4], ayh[4], ayl[4];
#pragma unroll
    for (int kc = 0; kc < 4; kc++) {
      int ko = kc * 32 + quad * 8;
      axh[kc] = *(const f16x8*)&AH[swz(ra, ko)];
      axl[kc] = *(const f16x8*)&AL[swz(ra, ko)];
      ayh[kc] = *(const f16x8*)&DH[swz(ra, ko)];
      ayl[kc] = *(const f16x8*)&DL[swz(ra, ko)];
    }
    __syncthreads();  // W3c0 drained; act planes reusable
    const float* b3d = b3 + d * Hh;
    const float* w4d = W4 + d * Hh;
    float psr = 0.f, psd = 0.f;
#pragma unroll 1
    for (int c = 0; c < 4; c++) {
      f32x4 aP = zero, aS = zero, dP = zero, dS = zero;
      mid_chunk(Ws, axh, axl, ayh, ayl, hrc, quad, aP, aS, dP, dS);
      if (c < 3) {
        __syncthreads();
        cp_lds_async512(wd + 49152 + (c + 1) * 8192, Ws, 16384, tid);
      }
      {
        int hb = c * 32 + wq * 16 + quad * 4;
        float4 bv4 = *(const float4*)&b3d[hb];
        float4 wv4 = *(const float4*)&w4d[hb];
#pragma unroll
        for (int j = 0; j < 4; j++) {
          float p = aP[j] + aS[j] * INV2K + (&bv4.x)[j];
          float s = p > 0.f ? 1.f : SLP;
          psr += p * s * (&wv4.x)[j];
          psd += s * (dP[j] + dS[j] * INV2K) * (&wv4.x)[j];
        }
      }
      if (c < 3) __syncthreads();
    }
    // quad-axis butterfly then one tiny LDS exchange across the wq pair
    psr += __shfl_xor(psr, 16); psr += __shfl_xor(psr, 32);
    psd += __shfl_xor(psd, 16); psd += __shfl_xor(psd, 32);
    float* xch = (float*)dsm;  // 64x2 f32 in the now-dead act region
    __syncthreads();           // all chunk reads finished before dsm reuse
    if (wq == 1 && quad == 0) {
      xch[ra * 2] = psr;
      xch[ra * 2 + 1] = psd;
    }
    __syncthreads();
    if (wq == 0 && quad == 0) {
      float sr = psr + xch[ra * 2];
      float sd = psd + xch[ra * 2 + 1];
      int ng = n0 + ra;
      out_res[ng * 64 + d] = sr + b4[d];
      atomicAdd(&out_log[ng], logf(fabsf(sd) + 1e-8f));
    }
  }
}

// ------------- fallback path (no workspace; raw weights; 256 threads) -------
__device__ __forceinline__ void stage_wf(f16* WH, f16* WL,
                                         const float* __restrict__ g, int tid) {
  for (int i = tid; i < 2048; i += 256) {
    int h = i >> 5, k4 = (i & 31) << 2;
    float4 v = ((const float4*)g)[i];
    HL a = split(v.x), b = split(v.y), c = split(v.z), e = split(v.w);
    int o = swz(h, k4);
    *(f16x4*)&WH[o] = f16x4{a.h, b.h, c.h, e.h};
    *(f16x4*)&WL[o] = f16x4{a.l, b.l, c.l, e.l};
  }
}

__device__ __forceinline__ void mid_mfma_half(
    const f16* AH, const f16* AL, const f16* DH, const f16* DL,
    const f16* WH, const f16* WL, int nt, int wq, int l15, int quad,
    f32x4* aP, f32x4* aS, f32x4* dP, f32x4* dS) {
#pragma unroll
  for (int kc = 0; kc < 4; kc++) {
    int ko = kc * 32 + quad * 8;
    int ra = nt * 16 + l15;
    f16x8 xh = *(const f16x8*)&AH[swz(ra, ko)];
    f16x8 xl = *(const f16x8*)&AL[swz(ra, ko)];
    f16x8 yh = *(const f16x8*)&DH[swz(ra, ko)];
    f16x8 yl = *(const f16x8*)&DL[swz(ra, ko)];
#pragma unroll
    for (int c2 = 0; c2 < 2; c2++) {
      int hr = (2 * wq + c2) * 16 + l15;
      f16x8 wh = *(const f16x8*)&WH[swz(hr, ko)];
      f16x8 wl = *(const f16x8*)&WL[swz(hr, ko)];
      aP[c2] = MFMA(wh, xh, aP[c2]);
      aS[c2] = MFMA(wl, xh, aS[c2]);
      aS[c2] = MFMA(wh, xl, aS[c2]);
      dP[c2] = MFMA(wh, yh, dP[c2]);
      dS[c2] = MFMA(wl, yh, dS[c2]);
      dS[c2] = MFMA(wh, yl, dS[c2]);
    }
  }
}

__global__ __launch_bounds__(256, 2)
void np_prior_fb(const float* __restrict__ x,
                 const float* __restrict__ W1, const float* __restrict__ b1,
                 const float* __restrict__ W2, const float* __restrict__ b2,
                 const float* __restrict__ W3, const float* __restrict__ b3,
                 const float* __restrict__ W4, const float* __restrict__ b4,
                 float* __restrict__ out_res, float* __restrict__ out_log) {
  __shared__ float4 smem[4096];
  f16* AH = (f16*)smem;
  f16* AL = AH + NT * 128;
  f16* DH = AL + NT * 128;
  f16* DL = DH + NT * 128;
  f16* WHp = (f16*)((char*)smem + 32768);
  f16* WLp = WHp + 64 * 128;
  float* A3F = (float*)smem;
  float* D3F = (float*)((char*)smem + 16384);

  const int tid = threadIdx.x, d = blockIdx.y, n0 = blockIdx.x * NT;
  const int lane = tid & 63, wv = tid >> 6, l15 = lane & 15, quad = lane >> 4;
  const int nt = wv & 1, wq = wv >> 1;

  const float* W1d = W1 + d * Hh * 65;
  const float* b1d = b1 + d * Hh;
  const f32x4 zero = {0.f, 0.f, 0.f, 0.f};

  for (int i = tid; i < NT * 16; i += 256) {
    int n = i >> 4, k4 = (i & 15) << 2;
    int ng = n0 + n, bb = ng >> 8, tt = ng & 255;
    float4 v = *(const float4*)&x[(bb * 257 + tt) * 64 + k4];
    HL a = split(v.x), b = split(v.y), c = split(v.z), e = split(v.w);
    int o = swz(n, k4);
    *(f16x4*)&AH[o] = f16x4{a.h, b.h, c.h, e.h};
    *(f16x4*)&AL[o] = f16x4{a.l, b.l, c.l, e.l};
  }
  float xtv;
  {
    int ng = n0 + nt * 16 + l15, bb = ng >> 8, tt = ng & 255;
    xtv = x[(bb * 257 + tt + 1) * 64 + d];
  }
  for (int i = tid; i < 64 * 64; i += 256) {
    int h = i >> 6, k = i & 63;
    HL s = split(W1d[h * 65 + k]);
    int o = swz(h, k);
    WHp[o] = s.h; WLp[o] = s.l;
  }
  __syncthreads();

  f32x4 l1P[2][2], l1S[2][2];
  for (int hf = 0; hf < 2; hf++) {
    if (hf == 1) {
      __syncthreads();
      for (int i = tid; i < 64 * 64; i += 256) {
        int h = i >> 6, k = i & 63;
        HL s = split(W1d[(64 + h) * 65 + k]);
        int o = swz(h, k);
        WHp[o] = s.h; WLp[o] = s.l;
      }
      __syncthreads();
    }
    l1P[hf][0] = zero; l1P[hf][1] = zero;
    l1S[hf][0] = zero; l1S[hf][1] = zero;
#pragma unroll
    for (int kc = 0; kc < 2; kc++) {
      int ko = kc * 32 + quad * 8;
      f16x8 xh = *(const f16x8*)&AH[swz(nt * 16 + l15, ko)];
      f16x8 xl = *(const f16x8*)&AL[swz(nt * 16 + l15, ko)];
#pragma unroll
      for (int c2 = 0; c2 < 2; c2++) {
        int hr = (2 * wq + c2) * 16 + l15;
        f16x8 wh = *(const f16x8*)&WHp[swz(hr, ko)];
        f16x8 wl = *(const f16x8*)&WLp[swz(hr, ko)];
        l1P[hf][c2] = MFMA(wh, xh, l1P[hf][c2]);
        l1S[hf][c2] = MFMA(wl, xh, l1S[hf][c2]);
        l1S[hf][c2] = MFMA(wh, xl, l1S[hf][c2]);
      }
    }
  }
  __syncthreads();

  {
    int n = nt * 16 + l15;
#pragma unroll
    for (int hf = 0; hf < 2; hf++)
#pragma unroll
      for (int c2 = 0; c2 < 2; c2++) {
        int hb = hf * 64 + (2 * wq + c2) * 16 + quad * 4;
        f16x4 ah, al, dh, dl;
#pragma unroll
        for (int j = 0; j < 4; j++) {
          int h = hb + j;
          float w1j = W1d[h * 65 + 64];
          float p = l1P[hf][c2][j] + l1S[hf][c2][j] * INV2K + xtv * w1j + b1d[h];
          float s = p > 0.f ? 1.f : SLP;
          HL av = split(p * s), dv = split(s * w1j);
          ah[j] = av.h; al[j] = av.l; dh[j] = dv.h; dl[j] = dv.l;
        }
        int o = swz(n, hb);
        *(f16x4*)&AH[o] = ah; *(f16x4*)&AL[o] = al;
        *(f16x4*)&DH[o] = dh; *(f16x4*)&DL[o] = dl;
      }
  }
  stage_wf(WHp, WLp, W2 + d * Hh * Hh, tid);
  __syncthreads();

  f32x4 aP[2][2], aS[2][2], dP[2][2], dS[2][2];
  for (int hf = 0; hf < 2; hf++) {
    if (hf == 1) {
      __syncthreads();
      stage_wf(WHp, WLp, W2 + d * Hh * Hh + 64 * 128, tid);
      __syncthreads();
    }
    aP[hf][0] = zero; aP[hf][1] = zero; aS[hf][0] = zero; aS[hf][1] = zero;
    dP[hf][0] = zero; dP[hf][1] = zero; dS[hf][0] = zero; dS[hf][1] = zero;
    mid_mfma_half(AH, AL, DH, DL, WHp, WLp, nt, wq, l15, quad,
                  aP[hf], aS[hf], dP[hf], dS[hf]);
  }
  __syncthreads();

  {
    const float* b2d = b2 + d * Hh;
    int n = nt * 16 + l15;
#pragma unroll
    for (int hf = 0; hf < 2; hf++)
#pragma unroll
      for (int c2 = 0; c2 < 2; c2++) {
        int hb = hf * 64 + (2 * wq + c2) * 16 + quad * 4;
        f16x4 ah, al, dh, dl;
#pragma unroll
        for (int j = 0; j < 4; j++) {
          int h = hb + j;
          float p = aP[hf][c2][j] + aS[hf][c2][j] * INV2K + b2d[h];
          float s = p > 0.f ? 1.f : SLP;
          float dd = s * (dP[hf][c2][j] + dS[hf][c2][j] * INV2K);
          HL av = split(p * s), dv = split(dd);
          ah[j] = av.h; al[j] = av.l; dh[j] = dv.h; dl[j] = dv.l;
        }
        int o = swz(n, hb);
        *(f16x4*)&AH[o] = ah; *(f16x4*)&AL[o] = al;
        *(f16x4*)&DH[o] = dh; *(f16x4*)&DL[o] = dl;
      }
  }
  stage_wf(WHp, WLp, W3 + d * Hh * Hh, tid);
  __syncthreads();

  for (int hf = 0; hf < 2; hf++) {
    if (hf == 1) {
      __syncthreads();
      stage_wf(WHp, WLp, W3 + d * Hh * Hh + 64 * 128, tid);
      __syncthreads();
    }
    aP[hf][0] = zero; aP[hf][1] = zero; aS[hf][0] = zero; aS[hf][1] = zero;
    dP[hf][0] = zero; dP[hf][1] = zero; dS[hf][0] = zero; dS[hf][1] = zero;
    mid_mfma_half(AH, AL, DH, DL, WHp, WLp, nt, wq, l15, quad,
                  aP[hf], aS[hf], dP[hf], dS[hf]);
  }
  __syncthreads();

  {
    const float* b3d = b3 + d * Hh;
    int n = nt * 16 + l15;
#pragma unroll
    for (int hf = 0; hf < 2; hf++)
#pragma unroll
      for (int c2 = 0; c2 < 2; c2++) {
        int hb = hf * 64 + (2 * wq + c2) * 16 + quad * 4;
        float4 pa, pd;
#pragma unroll
        for (int j = 0; j < 4; j++) {
          int h = hb + j;
          float p = aP[hf][c2][j] + aS[hf][c2][j] * INV2K + b3d[h];
          float s = p > 0.f ? 1.f : SLP;
          (&pa.x)[j] = p * s;
          (&pd.x)[j] = s * (dP[hf][c2][j] + dS[hf][c2][j] * INV2K);
        }
        *(float4*)&A3F[swzF(n, hb)] = pa;
        *(float4*)&D3F[swzF(n, hb)] = pd;
      }
  }
  __syncthreads();

  {
    int n = tid >> 3, oct = tid & 7;
    const float* w4d = W4 + d * Hh;
    float sr = 0.f, sd = 0.f;
#pragma unroll
    for (int i = 0; i < 4; i++) {
      int c = oct * 16 + i * 4;
      float4 va = *(const float4*)&A3F[swzF(n, c)];
      float4 vd = *(const float4*)&D3F[swzF(n, c)];
      float4 w = *(const float4*)&w4d[c];
      sr += va.x * w.x + va.y * w.y + va.z * w.z + va.w * w.w;
      sd += vd.x * w.x + vd.y * w.y + vd.z * w.z + vd.w * w.w;
    }
    sr += __shfl_xor(sr, 1); sr += __shfl_xor(sr, 2); sr += __shfl_xor(sr, 4);
    sd += __shfl_xor(sd, 1); sd += __shfl_xor(sd, 2); sd += __shfl_xor(sd, 4);
    if (oct == 0) {
      int ng = n0 + n;
      out_res[ng * 64 + d] = sr + b4[d];
      atomicAdd(&out_log[ng], logf(fabsf(sd) + 1e-8f));
    }
  }
}

extern "C" void kernel_launch(void* const* d_in, const int* in_sizes, int n_in,
                              void* d_out, int out_size, void* d_ws, size_t ws_size,
                              hipStream_t stream) {
  (void)in_sizes; (void)n_in; (void)out_size;
  const float* x  = (const float*)d_in[0];
  const float* W1 = (const float*)d_in[1];
  const float* b1 = (const float*)d_in[2];
  const float* W2 = (const float*)d_in[3];
  const float* b2 = (const float*)d_in[4];
  const float* W3 = (const float*)d_in[5];
  const float* b3 = (const float*)d_in[6];
  const float* W4 = (const float*)d_in[7];
  const float* b4 = (const float*)d_in[8];

  float* out_res = (float*)d_out;
  float* out_log = out_res + Nn * Dd;

  static int big_lds = -1;
  if (big_lds < 0) {
    big_lds = (hipFuncSetAttribute(
                   (const void*)np_prior_v7,
                   hipFuncAttributeMaxDynamicSharedMemorySize, 81920) ==
               hipSuccess)
                  ? 1
                  : 0;
  }

  if (ws_size >= WS_NEEDED && big_lds == 1) {
    f16* wsf = (f16*)d_ws;
    float* w1lg = (float*)((char*)d_ws + W1L_OFF);
    prep_kernel<<<2560, 256, 0, stream>>>(W1, W2, W3, wsf, w1lg, out_log);
    dim3 grid(Nn / 64, Dd);
    np_prior_v7<<<grid, 512, 81920, stream>>>(x, wsf, w1lg, b1, b2, b3, W4,
                                              b4, out_res, out_log);
  } else {
    hipMemsetAsync(out_log, 0, Nn * sizeof(float), stream);
    dim3 grid(Nn / NT, Dd);
    np_prior_fb<<<grid, 256, 0, stream>>>(x, W1, b1, W2, b2, W3, b3, W4, b4,
                                          out_res, out_log);
  }
}